// Round 5
// baseline (1008.730 us; speedup 1.0000x reference)
//
#include <hip/hip_runtime.h>

#define T_TOK 8192
#define H_DIM 1024
#define I_DIM 3584
#define NEXP 8
#define MAX_TILES 136          // sum ceil(cnt_e/128) <= 128 + 7, padded

typedef __attribute__((ext_vector_type(4))) float f32x4;
typedef __attribute__((ext_vector_type(8))) short bf16x8;

__device__ __forceinline__ unsigned short f2bf(float f) {
    union { float f; unsigned u; } v; v.f = f;
    unsigned r = v.u + 0x7FFFu + ((v.u >> 16) & 1u);
    return (unsigned short)(r >> 16);
}

__device__ __forceinline__ void gload16(const unsigned short* g, unsigned short* l) {
    __builtin_amdgcn_global_load_lds(
        (const __attribute__((address_space(1))) void*)g,
        (__attribute__((address_space(3))) void*)l, 16, 0, 0);
}

// ================= fast path =================

// router: logits -> softmax -> top2; emits pair[t], combine[t][8], and xb (bf16 x)
__global__ void router_kernel(const float* __restrict__ x, const float* __restrict__ gw,
                              const float* __restrict__ gb, unsigned short* __restrict__ xb,
                              float* __restrict__ combine, int* __restrict__ pair) {
    int wave = threadIdx.x >> 6, lane = threadIdx.x & 63;
    int t = blockIdx.x * 4 + wave;
    float acc[NEXP];
#pragma unroll
    for (int e = 0; e < NEXP; ++e) acc[e] = 0.f;
    const float4* xr = (const float4*)(x + (size_t)t * H_DIM);
#pragma unroll
    for (int j = 0; j < 4; ++j) {
        int c = j * 64 + lane;
        float4 xv = xr[c];
        ushort4 o = { f2bf(xv.x), f2bf(xv.y), f2bf(xv.z), f2bf(xv.w) };
        *(ushort4*)(xb + (size_t)t * H_DIM + c * 4) = o;
#pragma unroll
        for (int e = 0; e < NEXP; ++e) {
            float4 gv = ((const float4*)(gw + (size_t)e * H_DIM))[c];
            acc[e] += xv.x * gv.x + xv.y * gv.y + xv.z * gv.z + xv.w * gv.w;
        }
    }
#pragma unroll
    for (int off = 32; off; off >>= 1)
#pragma unroll
        for (int e = 0; e < NEXP; ++e) acc[e] += __shfl_xor(acc[e], off, 64);
    if (lane == 0) {
        float logit[NEXP], mx = -1e30f;
#pragma unroll
        for (int e = 0; e < NEXP; ++e) { logit[e] = acc[e] + gb[e]; mx = fmaxf(mx, logit[e]); }
        float p[NEXP], s = 0.f;
#pragma unroll
        for (int e = 0; e < NEXP; ++e) { p[e] = expf(logit[e] - mx); s += p[e]; }
        float inv = 1.f / s;
#pragma unroll
        for (int e = 0; e < NEXP; ++e) p[e] *= inv;
        int i1 = 0;
#pragma unroll
        for (int e = 1; e < NEXP; ++e) if (p[e] > p[i1]) i1 = e;
        int i2 = -1;
#pragma unroll
        for (int e = 0; e < NEXP; ++e) if (e != i1 && (i2 < 0 || p[e] > p[i2])) i2 = e;
        float4 c0, c1;
        c0.x = (0 == i1 || 0 == i2) ? p[0] : 0.f;  c0.y = (1 == i1 || 1 == i2) ? p[1] : 0.f;
        c0.z = (2 == i1 || 2 == i2) ? p[2] : 0.f;  c0.w = (3 == i1 || 3 == i2) ? p[3] : 0.f;
        c1.x = (4 == i1 || 4 == i2) ? p[4] : 0.f;  c1.y = (5 == i1 || 5 == i2) ? p[5] : 0.f;
        c1.z = (6 == i1 || 6 == i2) ? p[6] : 0.f;  c1.w = (7 == i1 || 7 == i2) ? p[7] : 0.f;
        *(float4*)(combine + (size_t)t * NEXP) = c0;
        *(float4*)(combine + (size_t)t * NEXP + 4) = c1;
        pair[t] = i1 | (i2 << 8);
    }
}

// deterministic, atomic-free list builder: 8 blocks (one per expert), 1024 threads.
__global__ void build_lists_kernel(const int* __restrict__ pair, int* __restrict__ frows,
                                   int* __restrict__ tile_e, int* __restrict__ tile_valid,
                                   int* __restrict__ ntiles) {
    const int e = blockIdx.x;
    const int tid = threadIdx.x;
    const int wave = tid >> 6, lane = tid & 63;
    __shared__ int wtot[16][NEXP];
    __shared__ int stot[NEXP];
    __shared__ int wcnt[16];

    int myp[8];
    int tcnt[NEXP] = {0, 0, 0, 0, 0, 0, 0, 0};
#pragma unroll
    for (int c = 0; c < 8; ++c) {
        int pr = pair[c * 1024 + tid];
        myp[c] = pr;
        int e1 = pr & 255, e2 = (pr >> 8) & 255;
#pragma unroll
        for (int j = 0; j < NEXP; ++j) {
            unsigned long long m = __ballot(e1 == j || e2 == j);
            if (lane == 0) tcnt[j] += (int)__popcll(m);
        }
    }
    if (lane == 0) {
#pragma unroll
        for (int j = 0; j < NEXP; ++j) wtot[wave][j] = tcnt[j];
    }
    __syncthreads();
    if (tid < NEXP) {
        int s = 0;
        for (int w = 0; w < 16; ++w) s += wtot[w][tid];
        stot[tid] = s;
    }
    __syncthreads();

    int gbase = 0, tbase = 0, totTiles = 0;
#pragma unroll
    for (int j = 0; j < NEXP; ++j) {
        int tj = (stot[j] + 127) >> 7;
        if (j < e) { gbase += tj << 7; tbase += tj; }
        totTiles += tj;
    }
    const int cnt = stot[e];
    const int mytiles = (cnt + 127) >> 7;

    int base = gbase;
    for (int c = 0; c < 8; ++c) {
        int pr = myp[c];
        bool pred = ((pr & 255) == e) || (((pr >> 8) & 255) == e);
        unsigned long long m = __ballot(pred);
        if (lane == 0) wcnt[wave] = (int)__popcll(m);
        __syncthreads();
        int wb = 0;
        for (int w = 0; w < wave; ++w) wb += wcnt[w];
        int ctot = 0;
        for (int w = 0; w < 16; ++w) ctot += wcnt[w];
        if (pred) {
            int wp = (int)__popcll(m & ((1ull << lane) - 1ull));
            frows[base + wb + wp] = c * 1024 + tid;
        }
        base += ctot;
        __syncthreads();
    }
    if (cnt > 0) {
        int first = frows[gbase];
        for (int p = cnt + tid; p < (mytiles << 7); p += 1024) frows[gbase + p] = first;
        if (tid < mytiles) {
            tile_e[tbase + tid] = e;
            int v = cnt - (tid << 7);
            tile_valid[tbase + tid] = v > 128 ? 128 : v;
        }
    }
    if (e == 0 && tid == 0) ntiles[0] = totTiles;
}

// weights f32 -> bf16 (grid-stride, 8 elems/thread)
__global__ void wcvt_kernel(const float* __restrict__ src, unsigned short* __restrict__ dst, int n8) {
    int stride = gridDim.x * blockDim.x;
    for (int i = blockIdx.x * blockDim.x + threadIdx.x; i < n8; i += stride) {
        const float4* p = (const float4*)src + (size_t)i * 2;
        float4 a = p[0], b = p[1];
        uint4 o;
        o.x = (unsigned)f2bf(a.x) | ((unsigned)f2bf(a.y) << 16);
        o.y = (unsigned)f2bf(a.z) | ((unsigned)f2bf(a.w) << 16);
        o.z = (unsigned)f2bf(b.x) | ((unsigned)f2bf(b.y) << 16);
        o.w = (unsigned)f2bf(b.z) | ((unsigned)f2bf(b.w) << 16);
        *(uint4*)(dst + (size_t)i * 8) = o;
    }
}

// GEMM1 (flat over all experts): h = silu(Xg*W1e^T) * (Xg*W3e^T)
// LDS bank-conflict fix (T2 via rule 21): linear gload_lds dest + inverse-swizzled
// global SOURCE (srcslot = (lane&7) ^ (lane>>3)) + XOR-swizzled ds_read addresses.
__global__ __launch_bounds__(256, 3)
void gemm1_kernel(const unsigned short* __restrict__ xb,
                  const unsigned short* __restrict__ w1b, const unsigned short* __restrict__ w3b,
                  unsigned short* __restrict__ h_bf,
                  const int* __restrict__ frows, const int* __restrict__ tile_e,
                  const int* __restrict__ ntiles) {
    const int bt = blockIdx.y;
    if (bt >= ntiles[0]) return;
    __shared__ unsigned short aT[128 * 64];
    __shared__ unsigned short b1T[128 * 64];
    __shared__ unsigned short b3T[128 * 64];
    const int e = tile_e[bt];
    const int n0 = blockIdx.x * 128;
    const int tid = threadIdx.x, wave = tid >> 6, lane = tid & 63;
    const int wm = wave >> 1, wn = wave & 1;

    // source swizzle: lane l stages global slot ((l&7)^(l>>3)) into linear LDS pos (l&7)
    const int sslot = (lane & 7) ^ (lane >> 3);
    const unsigned short *aS[4], *b1S[4], *b3S[4];
    unsigned short *aD[4], *b1D[4], *b3D[4];
#pragma unroll
    for (int i = 0; i < 4; ++i) {
        int rowl = wave * 32 + i * 8 + (lane >> 3);
        int tok = frows[bt * 128 + rowl];
        int c8 = sslot * 8;
        aS[i]  = xb  + (size_t)tok * H_DIM + c8;
        b1S[i] = w1b + ((size_t)e * I_DIM + n0 + rowl) * H_DIM + c8;
        b3S[i] = w3b + ((size_t)e * I_DIM + n0 + rowl) * H_DIM + c8;
        int r0l = wave * 32 + i * 8;
        aD[i] = &aT[r0l * 64]; b1D[i] = &b1T[r0l * 64]; b3D[i] = &b3T[r0l * 64];
    }
    f32x4 acc1[4][4] = {};
    f32x4 acc3[4][4] = {};

    for (int kt = 0; kt < H_DIM / 64; ++kt) {
#pragma unroll
        for (int i = 0; i < 4; ++i) {
            gload16(aS[i], aD[i]);
            gload16(b1S[i], b1D[i]);
            gload16(b3S[i], b3D[i]);
            aS[i] += 64; b1S[i] += 64; b3S[i] += 64;
        }
        __syncthreads();
#pragma unroll
        for (int ks = 0; ks < 2; ++ks) {
            const int slot = ks * 4 + (lane >> 4);
            bf16x8 af[4], b1f[4], b3f[4];
#pragma unroll
            for (int m = 0; m < 4; ++m) {
                int row = wm * 64 + m * 16 + (lane & 15);
                af[m] = *(const bf16x8*)&aT[row * 64 + ((slot ^ (row & 7)) << 3)];
            }
#pragma unroll
            for (int n = 0; n < 4; ++n) {
                int row = wn * 64 + n * 16 + (lane & 15);
                int offr = row * 64 + ((slot ^ (row & 7)) << 3);
                b1f[n] = *(const bf16x8*)&b1T[offr];
                b3f[n] = *(const bf16x8*)&b3T[offr];
            }
#pragma unroll
            for (int m = 0; m < 4; ++m)
#pragma unroll
                for (int n = 0; n < 4; ++n) {
                    acc1[m][n] = __builtin_amdgcn_mfma_f32_16x16x32_bf16(af[m], b1f[n], acc1[m][n], 0, 0, 0);
                    acc3[m][n] = __builtin_amdgcn_mfma_f32_16x16x32_bf16(af[m], b3f[n], acc3[m][n], 0, 0, 0);
                }
        }
        __syncthreads();
    }
#pragma unroll
    for (int m = 0; m < 4; ++m)
#pragma unroll
        for (int r = 0; r < 4; ++r) {
            int rowl = wm * 64 + m * 16 + (lane >> 4) * 4 + r;
            size_t hoff = (size_t)(bt * 128 + rowl) * I_DIM;
#pragma unroll
            for (int n = 0; n < 4; ++n) {
                int col = n0 + wn * 64 + n * 16 + (lane & 15);
                float v1 = acc1[m][n][r], v3 = acc3[m][n][r];
                float hv = (v1 / (1.f + expf(-v1))) * v3;
                h_bf[hoff + col] = f2bf(hv);
            }
        }
}

// GEMM2 (flat): out[t,:] += combine[t,e] * (Hg * W2e^T); same swizzle scheme.
// atomicAdd writeback: exactly 2 contributions per element onto zeroed out;
// f32 add commutes => deterministic.
__global__ __launch_bounds__(256, 3)
void gemm2_kernel(const unsigned short* __restrict__ h_bf, const unsigned short* __restrict__ w2b,
                  const float* __restrict__ combine, float* __restrict__ out,
                  const int* __restrict__ frows, const int* __restrict__ tile_e,
                  const int* __restrict__ tile_valid, const int* __restrict__ ntiles) {
    const int bt = blockIdx.y;
    if (bt >= ntiles[0]) return;
    __shared__ unsigned short aT[128 * 64];
    __shared__ unsigned short bT[128 * 64];
    const int e = tile_e[bt];
    const int valid = tile_valid[bt];
    const int n0 = blockIdx.x * 128;
    const int tid = threadIdx.x, wave = tid >> 6, lane = tid & 63;
    const int wm = wave >> 1, wn = wave & 1;

    const int sslot = (lane & 7) ^ (lane >> 3);
    const unsigned short *aS[4], *bS[4];
    unsigned short *aD[4], *bD[4];
#pragma unroll
    for (int i = 0; i < 4; ++i) {
        int rowl = wave * 32 + i * 8 + (lane >> 3);
        int c8 = sslot * 8;
        aS[i] = h_bf + (size_t)(bt * 128 + rowl) * I_DIM + c8;
        bS[i] = w2b + ((size_t)e * H_DIM + n0 + rowl) * I_DIM + c8;
        int r0l = wave * 32 + i * 8;
        aD[i] = &aT[r0l * 64]; bD[i] = &bT[r0l * 64];
    }
    f32x4 acc[4][4] = {};

    for (int kt = 0; kt < I_DIM / 64; ++kt) {
#pragma unroll
        for (int i = 0; i < 4; ++i) {
            gload16(aS[i], aD[i]);
            gload16(bS[i], bD[i]);
            aS[i] += 64; bS[i] += 64;
        }
        __syncthreads();
#pragma unroll
        for (int ks = 0; ks < 2; ++ks) {
            const int slot = ks * 4 + (lane >> 4);
            bf16x8 af[4], bfr[4];
#pragma unroll
            for (int m = 0; m < 4; ++m) {
                int row = wm * 64 + m * 16 + (lane & 15);
                af[m] = *(const bf16x8*)&aT[row * 64 + ((slot ^ (row & 7)) << 3)];
            }
#pragma unroll
            for (int n = 0; n < 4; ++n) {
                int row = wn * 64 + n * 16 + (lane & 15);
                bfr[n] = *(const bf16x8*)&bT[row * 64 + ((slot ^ (row & 7)) << 3)];
            }
#pragma unroll
            for (int m = 0; m < 4; ++m)
#pragma unroll
                for (int n = 0; n < 4; ++n)
                    acc[m][n] = __builtin_amdgcn_mfma_f32_16x16x32_bf16(af[m], bfr[n], acc[m][n], 0, 0, 0);
        }
        __syncthreads();
    }
#pragma unroll
    for (int m = 0; m < 4; ++m)
#pragma unroll
        for (int r = 0; r < 4; ++r) {
            int rowl = wm * 64 + m * 16 + (lane >> 4) * 4 + r;
            if (rowl < valid) {
                int t = frows[bt * 128 + rowl];
                float cmb = combine[(size_t)t * NEXP + e];
#pragma unroll
                for (int n = 0; n < 4; ++n) {
                    int col = n0 + wn * 64 + n * 16 + (lane & 15);
                    atomicAdd(&out[(size_t)t * H_DIM + col], cmb * acc[m][n][r]);
                }
            }
        }
}

// ================= fallback path (R1, verified) =================

__global__ void cvt_x_fb(const float* __restrict__ x, unsigned short* __restrict__ xb) {
    size_t i = (size_t)blockIdx.x * blockDim.x + threadIdx.x;
    const float4* p = (const float4*)x + i * 2;
    float4 a = p[0], b = p[1];
    uint4 o;
    o.x = (unsigned)f2bf(a.x) | ((unsigned)f2bf(a.y) << 16);
    o.y = (unsigned)f2bf(a.z) | ((unsigned)f2bf(a.w) << 16);
    o.z = (unsigned)f2bf(b.x) | ((unsigned)f2bf(b.y) << 16);
    o.w = (unsigned)f2bf(b.z) | ((unsigned)f2bf(b.w) << 16);
    *(uint4*)(xb + i * 8) = o;
}

__global__ void router_fb(const float* __restrict__ x, const float* __restrict__ gw,
                          const float* __restrict__ gb, float* __restrict__ combine,
                          int* __restrict__ rowlist, int* __restrict__ count) {
    int wave = threadIdx.x >> 6, lane = threadIdx.x & 63;
    int t = blockIdx.x * 4 + wave;
    float acc[NEXP];
#pragma unroll
    for (int e = 0; e < NEXP; ++e) acc[e] = 0.f;
    const float4* xr = (const float4*)(x + (size_t)t * H_DIM);
#pragma unroll
    for (int j = 0; j < 4; ++j) {
        int c = j * 64 + lane;
        float4 xv = xr[c];
#pragma unroll
        for (int e = 0; e < NEXP; ++e) {
            float4 gv = ((const float4*)(gw + (size_t)e * H_DIM))[c];
            acc[e] += xv.x * gv.x + xv.y * gv.y + xv.z * gv.z + xv.w * gv.w;
        }
    }
#pragma unroll
    for (int off = 32; off; off >>= 1)
#pragma unroll
        for (int e = 0; e < NEXP; ++e) acc[e] += __shfl_xor(acc[e], off, 64);
    if (lane == 0) {
        float logit[NEXP], mx = -1e30f;
#pragma unroll
        for (int e = 0; e < NEXP; ++e) { logit[e] = acc[e] + gb[e]; mx = fmaxf(mx, logit[e]); }
        float p[NEXP], s = 0.f;
#pragma unroll
        for (int e = 0; e < NEXP; ++e) { p[e] = expf(logit[e] - mx); s += p[e]; }
        float inv = 1.f / s;
#pragma unroll
        for (int e = 0; e < NEXP; ++e) p[e] *= inv;
        int i1 = 0;
#pragma unroll
        for (int e = 1; e < NEXP; ++e) if (p[e] > p[i1]) i1 = e;
        int i2 = -1;
#pragma unroll
        for (int e = 0; e < NEXP; ++e) if (e != i1 && (i2 < 0 || p[e] > p[i2])) i2 = e;
#pragma unroll
        for (int e = 0; e < NEXP; ++e)
            combine[(size_t)t * NEXP + e] = (e == i1 || e == i2) ? p[e] : 0.f;
        int pos1 = atomicAdd(&count[i1], 1); rowlist[i1 * T_TOK + pos1] = t;
        int pos2 = atomicAdd(&count[i2], 1); rowlist[i2 * T_TOK + pos2] = t;
    }
}

__global__ __launch_bounds__(256, 2)
void gemm1_fb(const unsigned short* __restrict__ x_bf,
              const float* __restrict__ w1, const float* __restrict__ w3,
              unsigned short* __restrict__ h_bf,
              const int* __restrict__ rowlist, const int* __restrict__ count, int e) {
    __shared__ unsigned short aT[128 * 64];
    __shared__ unsigned short b1T[128 * 64];
    __shared__ unsigned short b3T[128 * 64];
    __shared__ int rl[128];
    const int cnt = count[e];
    const int r0 = blockIdx.y * 128;
    if (r0 >= cnt) return;
    const int n0 = blockIdx.x * 128;
    const float* __restrict__ w1e = w1 + (size_t)e * I_DIM * H_DIM;
    const float* __restrict__ w3e = w3 + (size_t)e * I_DIM * H_DIM;
    const int tid = threadIdx.x;
    if (tid < 128) {
        int r = r0 + tid;
        rl[tid] = rowlist[e * T_TOK + (r < cnt ? r : 0)];
    }
    __syncthreads();
    const int wave = tid >> 6, lane = tid & 63;
    const int wm = wave >> 1, wn = wave & 1;
    f32x4 acc1[4][4] = {};
    f32x4 acc3[4][4] = {};

    for (int kt = 0; kt < H_DIM / 64; ++kt) {
        const int k0 = kt * 64;
#pragma unroll
        for (int it = 0; it < 4; ++it) {
            int c = it * 256 + tid, row = c >> 3, slot = c & 7;
            uint4 v = *(const uint4*)(x_bf + (size_t)rl[row] * H_DIM + k0 + slot * 8);
            *(uint4*)&aT[row * 64 + ((slot ^ (row & 7)) << 3)] = v;
        }
#pragma unroll
        for (int it = 0; it < 8; ++it) {
            int c = it * 256 + tid, row = c >> 4, cw = c & 15;
            size_t goff = (size_t)(n0 + row) * H_DIM + k0 + cw * 4;
            float4 v1 = *(const float4*)(w1e + goff);
            float4 v3 = *(const float4*)(w3e + goff);
            int offr = row * 64 + (((cw >> 1) ^ (row & 7)) << 3) + (cw & 1) * 4;
            ushort4 p1 = { f2bf(v1.x), f2bf(v1.y), f2bf(v1.z), f2bf(v1.w) };
            ushort4 p3 = { f2bf(v3.x), f2bf(v3.y), f2bf(v3.z), f2bf(v3.w) };
            *(ushort4*)&b1T[offr] = p1;
            *(ushort4*)&b3T[offr] = p3;
        }
        __syncthreads();
#pragma unroll
        for (int ks = 0; ks < 2; ++ks) {
            const int slot = ks * 4 + (lane >> 4);
            bf16x8 af[4], b1f[4], b3f[4];
#pragma unroll
            for (int m = 0; m < 4; ++m) {
                int row = wm * 64 + m * 16 + (lane & 15);
                af[m] = *(const bf16x8*)&aT[row * 64 + ((slot ^ (row & 7)) << 3)];
            }
#pragma unroll
            for (int n = 0; n < 4; ++n) {
                int row = wn * 64 + n * 16 + (lane & 15);
                int offr = row * 64 + ((slot ^ (row & 7)) << 3);
                b1f[n] = *(const bf16x8*)&b1T[offr];
                b3f[n] = *(const bf16x8*)&b3T[offr];
            }
#pragma unroll
            for (int m = 0; m < 4; ++m)
#pragma unroll
                for (int n = 0; n < 4; ++n) {
                    acc1[m][n] = __builtin_amdgcn_mfma_f32_16x16x32_bf16(af[m], b1f[n], acc1[m][n], 0, 0, 0);
                    acc3[m][n] = __builtin_amdgcn_mfma_f32_16x16x32_bf16(af[m], b3f[n], acc3[m][n], 0, 0, 0);
                }
        }
        __syncthreads();
    }
#pragma unroll
    for (int m = 0; m < 4; ++m)
#pragma unroll
        for (int r = 0; r < 4; ++r) {
            int rowl = wm * 64 + m * 16 + (lane >> 4) * 4 + r;
            int ridx = r0 + rowl;
            if (ridx < cnt) {
#pragma unroll
                for (int n = 0; n < 4; ++n) {
                    int col = n0 + wn * 64 + n * 16 + (lane & 15);
                    float v1 = acc1[m][n][r], v3 = acc3[m][n][r];
                    float hv = (v1 / (1.f + expf(-v1))) * v3;
                    h_bf[(size_t)ridx * I_DIM + col] = f2bf(hv);
                }
            }
        }
}

__global__ __launch_bounds__(256, 2)
void gemm2_fb(const unsigned short* __restrict__ h_bf, const float* __restrict__ w2,
              const float* __restrict__ combine, float* __restrict__ out,
              const int* __restrict__ rowlist, const int* __restrict__ count, int e) {
    __shared__ unsigned short aT[128 * 64];
    __shared__ unsigned short bT[128 * 64];
    __shared__ int rl[128];
    const int cnt = count[e];
    const int r0 = blockIdx.y * 128;
    if (r0 >= cnt) return;
    const int n0 = blockIdx.x * 128;
    const float* __restrict__ w2e = w2 + (size_t)e * H_DIM * I_DIM;
    const int tid = threadIdx.x;
    if (tid < 128) {
        int r = r0 + tid;
        rl[tid] = rowlist[e * T_TOK + (r < cnt ? r : 0)];
    }
    __syncthreads();
    const int wave = tid >> 6, lane = tid & 63;
    const int wm = wave >> 1, wn = wave & 1;
    f32x4 acc[4][4] = {};

    for (int kt = 0; kt < I_DIM / 64; ++kt) {
        const int k0 = kt * 64;
#pragma unroll
        for (int it = 0; it < 4; ++it) {
            int c = it * 256 + tid, row = c >> 3, slot = c & 7;
            uint4 v = *(const uint4*)(h_bf + (size_t)(r0 + row) * I_DIM + k0 + slot * 8);
            *(uint4*)&aT[row * 64 + ((slot ^ (row & 7)) << 3)] = v;
        }
#pragma unroll
        for (int it = 0; it < 8; ++it) {
            int c = it * 256 + tid, row = c >> 4, cw = c & 15;
            float4 v = *(const float4*)(w2e + (size_t)(n0 + row) * I_DIM + k0 + cw * 4);
            int offr = row * 64 + (((cw >> 1) ^ (row & 7)) << 3) + (cw & 1) * 4;
            ushort4 p = { f2bf(v.x), f2bf(v.y), f2bf(v.z), f2bf(v.w) };
            *(ushort4*)&bT[offr] = p;
        }
        __syncthreads();
#pragma unroll
        for (int ks = 0; ks < 2; ++ks) {
            const int slot = ks * 4 + (lane >> 4);
            bf16x8 af[4], bfr[4];
#pragma unroll
            for (int m = 0; m < 4; ++m) {
                int row = wm * 64 + m * 16 + (lane & 15);
                af[m] = *(const bf16x8*)&aT[row * 64 + ((slot ^ (row & 7)) << 3)];
            }
#pragma unroll
            for (int n = 0; n < 4; ++n) {
                int row = wn * 64 + n * 16 + (lane & 15);
                bfr[n] = *(const bf16x8*)&bT[row * 64 + ((slot ^ (row & 7)) << 3)];
            }
#pragma unroll
            for (int m = 0; m < 4; ++m)
#pragma unroll
                for (int n = 0; n < 4; ++n)
                    acc[m][n] = __builtin_amdgcn_mfma_f32_16x16x32_bf16(af[m], bfr[n], acc[m][n], 0, 0, 0);
        }
        __syncthreads();
    }
#pragma unroll
    for (int m = 0; m < 4; ++m)
#pragma unroll
        for (int r = 0; r < 4; ++r) {
            int rowl = wm * 64 + m * 16 + (lane >> 4) * 4 + r;
            int ridx = r0 + rowl;
            if (ridx < cnt) {
                int t = rl[rowl];
                float cmb = combine[(size_t)t * NEXP + e];
#pragma unroll
                for (int n = 0; n < 4; ++n) {
                    int col = n0 + wn * 64 + n * 16 + (lane & 15);
                    out[(size_t)t * H_DIM + col] += cmb * acc[m][n][r];
                }
            }
        }
}

// ================= launch =================

extern "C" void kernel_launch(void* const* d_in, const int* in_sizes, int n_in,
                              void* d_out, int out_size, void* d_ws, size_t ws_size,
                              hipStream_t stream) {
    const float* x  = (const float*)d_in[0];
    const float* gw = (const float*)d_in[1];
    const float* gb = (const float*)d_in[2];
    const float* w1 = (const float*)d_in[3];
    const float* w2 = (const float*)d_in[4];
    const float* w3 = (const float*)d_in[5];
    float* out = (float*)d_out;
    char* ws = (char*)d_ws;

    const size_t WELEMS = (size_t)NEXP * I_DIM * H_DIM;      // 29,360,128
    // fast-path layout
    size_t off = 0;
    unsigned short* xb  = (unsigned short*)(ws + off); off += (size_t)T_TOK * H_DIM * 2;       // 16 MB
    unsigned short* w1b = (unsigned short*)(ws + off); off += WELEMS * 2;                      // 56 MB
    unsigned short* w3b = (unsigned short*)(ws + off); off += WELEMS * 2;
    unsigned short* w2b = (unsigned short*)(ws + off); off += WELEMS * 2;
    unsigned short* hb  = (unsigned short*)(ws + off); off += (size_t)MAX_TILES * 128 * I_DIM * 2; // 119 MB
    float* combine      = (float*)(ws + off);          off += (size_t)T_TOK * NEXP * 4;
    int* pair           = (int*)(ws + off);            off += (size_t)T_TOK * 4;
    int* frows          = (int*)(ws + off);            off += (size_t)MAX_TILES * 128 * 4;
    int* tile_e         = (int*)(ws + off);            off += 1024;
    int* tile_valid     = (int*)(ws + off);            off += 1024;
    int* ntiles         = (int*)(ws + off);            off += 1024;
    const size_t WS_NEEDED = off;

    (void)hipMemsetAsync(out, 0, (size_t)T_TOK * H_DIM * sizeof(float), stream);

    if (ws_size >= WS_NEEDED) {
        const int n8 = (int)(WELEMS / 8);
        wcvt_kernel<<<dim3(2048), dim3(256), 0, stream>>>(w1, w1b, n8);
        wcvt_kernel<<<dim3(2048), dim3(256), 0, stream>>>(w3, w3b, n8);
        wcvt_kernel<<<dim3(2048), dim3(256), 0, stream>>>(w2, w2b, n8);
        router_kernel<<<dim3(T_TOK / 4), dim3(256), 0, stream>>>(x, gw, gb, xb, combine, pair);
        build_lists_kernel<<<dim3(NEXP), dim3(1024), 0, stream>>>(pair, frows, tile_e, tile_valid, ntiles);
        gemm1_kernel<<<dim3(I_DIM / 128, MAX_TILES), dim3(256), 0, stream>>>(
            xb, w1b, w3b, hb, frows, tile_e, ntiles);
        gemm2_kernel<<<dim3(H_DIM / 128, MAX_TILES), dim3(256), 0, stream>>>(
            hb, w2b, combine, out, frows, tile_e, tile_valid, ntiles);
    } else {
        // fallback: R1 layout (76 MB)
        unsigned short* x_bf    = (unsigned short*)ws;
        unsigned short* h_bf    = (unsigned short*)(ws + 16777216);
        float*          fcomb   = (float*)(ws + 16777216 + 58720256);
        int*            rowlist = (int*)(ws + 16777216 + 58720256 + 262144);
        int*            count   = (int*)(ws + 16777216 + 58720256 + 262144 + 262144);

        (void)hipMemsetAsync(count, 0, NEXP * sizeof(int), stream);
        cvt_x_fb<<<dim3(T_TOK * H_DIM / (256 * 8)), dim3(256), 0, stream>>>(x, x_bf);
        router_fb<<<dim3(T_TOK / 4), dim3(256), 0, stream>>>(x, gw, gb, fcomb, rowlist, count);
        for (int e = 0; e < NEXP; ++e) {
            gemm1_fb<<<dim3(I_DIM / 128, T_TOK / 128), dim3(256), 0, stream>>>(
                x_bf, w1, w3, h_bf, rowlist, count, e);
            gemm2_fb<<<dim3(H_DIM / 128, T_TOK / 128), dim3(256), 0, stream>>>(
                h_bf, w2, fcomb, out, rowlist, count, e);
        }
    }
}

// Round 6
// 605.240 us; speedup vs baseline: 1.6667x; 1.6667x over previous
//
#include <hip/hip_runtime.h>

#define T_TOK 8192
#define H_DIM 1024
#define I_DIM 3584
#define NEXP 8
#define MAX_TILES 136          // sum ceil(cnt_e/128) <= 128 + 7, padded

typedef __attribute__((ext_vector_type(4))) float f32x4;
typedef __attribute__((ext_vector_type(8))) short bf16x8;

__device__ __forceinline__ unsigned short f2bf(float f) {
    union { float f; unsigned u; } v; v.f = f;
    unsigned r = v.u + 0x7FFFu + ((v.u >> 16) & 1u);
    return (unsigned short)(r >> 16);
}

__device__ __forceinline__ void gload16(const unsigned short* g, unsigned short* l) {
    __builtin_amdgcn_global_load_lds(
        (const __attribute__((address_space(1))) void*)g,
        (__attribute__((address_space(3))) void*)l, 16, 0, 0);
}

// ================= fast path =================

// router: logits -> softmax -> top2; emits pair[t], combine[t][8], and xb (bf16 x)
__global__ void router_kernel(const float* __restrict__ x, const float* __restrict__ gw,
                              const float* __restrict__ gb, unsigned short* __restrict__ xb,
                              float* __restrict__ combine, int* __restrict__ pair) {
    int wave = threadIdx.x >> 6, lane = threadIdx.x & 63;
    int t = blockIdx.x * 4 + wave;
    float acc[NEXP];
#pragma unroll
    for (int e = 0; e < NEXP; ++e) acc[e] = 0.f;
    const float4* xr = (const float4*)(x + (size_t)t * H_DIM);
#pragma unroll
    for (int j = 0; j < 4; ++j) {
        int c = j * 64 + lane;
        float4 xv = xr[c];
        ushort4 o = { f2bf(xv.x), f2bf(xv.y), f2bf(xv.z), f2bf(xv.w) };
        *(ushort4*)(xb + (size_t)t * H_DIM + c * 4) = o;
#pragma unroll
        for (int e = 0; e < NEXP; ++e) {
            float4 gv = ((const float4*)(gw + (size_t)e * H_DIM))[c];
            acc[e] += xv.x * gv.x + xv.y * gv.y + xv.z * gv.z + xv.w * gv.w;
        }
    }
#pragma unroll
    for (int off = 32; off; off >>= 1)
#pragma unroll
        for (int e = 0; e < NEXP; ++e) acc[e] += __shfl_xor(acc[e], off, 64);
    if (lane == 0) {
        float logit[NEXP], mx = -1e30f;
#pragma unroll
        for (int e = 0; e < NEXP; ++e) { logit[e] = acc[e] + gb[e]; mx = fmaxf(mx, logit[e]); }
        float p[NEXP], s = 0.f;
#pragma unroll
        for (int e = 0; e < NEXP; ++e) { p[e] = expf(logit[e] - mx); s += p[e]; }
        float inv = 1.f / s;
#pragma unroll
        for (int e = 0; e < NEXP; ++e) p[e] *= inv;
        int i1 = 0;
#pragma unroll
        for (int e = 1; e < NEXP; ++e) if (p[e] > p[i1]) i1 = e;
        int i2 = -1;
#pragma unroll
        for (int e = 0; e < NEXP; ++e) if (e != i1 && (i2 < 0 || p[e] > p[i2])) i2 = e;
        float4 c0, c1;
        c0.x = (0 == i1 || 0 == i2) ? p[0] : 0.f;  c0.y = (1 == i1 || 1 == i2) ? p[1] : 0.f;
        c0.z = (2 == i1 || 2 == i2) ? p[2] : 0.f;  c0.w = (3 == i1 || 3 == i2) ? p[3] : 0.f;
        c1.x = (4 == i1 || 4 == i2) ? p[4] : 0.f;  c1.y = (5 == i1 || 5 == i2) ? p[5] : 0.f;
        c1.z = (6 == i1 || 6 == i2) ? p[6] : 0.f;  c1.w = (7 == i1 || 7 == i2) ? p[7] : 0.f;
        *(float4*)(combine + (size_t)t * NEXP) = c0;
        *(float4*)(combine + (size_t)t * NEXP + 4) = c1;
        pair[t] = i1 | (i2 << 8);
    }
}

// deterministic, atomic-free list builder: 8 blocks (one per expert), 1024 threads.
__global__ void build_lists_kernel(const int* __restrict__ pair, int* __restrict__ frows,
                                   int* __restrict__ tile_e, int* __restrict__ tile_valid,
                                   int* __restrict__ ntiles) {
    const int e = blockIdx.x;
    const int tid = threadIdx.x;
    const int wave = tid >> 6, lane = tid & 63;
    __shared__ int wtot[16][NEXP];
    __shared__ int stot[NEXP];
    __shared__ int wcnt[16];

    int myp[8];
    int tcnt[NEXP] = {0, 0, 0, 0, 0, 0, 0, 0};
#pragma unroll
    for (int c = 0; c < 8; ++c) {
        int pr = pair[c * 1024 + tid];
        myp[c] = pr;
        int e1 = pr & 255, e2 = (pr >> 8) & 255;
#pragma unroll
        for (int j = 0; j < NEXP; ++j) {
            unsigned long long m = __ballot(e1 == j || e2 == j);
            if (lane == 0) tcnt[j] += (int)__popcll(m);
        }
    }
    if (lane == 0) {
#pragma unroll
        for (int j = 0; j < NEXP; ++j) wtot[wave][j] = tcnt[j];
    }
    __syncthreads();
    if (tid < NEXP) {
        int s = 0;
        for (int w = 0; w < 16; ++w) s += wtot[w][tid];
        stot[tid] = s;
    }
    __syncthreads();

    int gbase = 0, tbase = 0, totTiles = 0;
#pragma unroll
    for (int j = 0; j < NEXP; ++j) {
        int tj = (stot[j] + 127) >> 7;
        if (j < e) { gbase += tj << 7; tbase += tj; }
        totTiles += tj;
    }
    const int cnt = stot[e];
    const int mytiles = (cnt + 127) >> 7;

    int base = gbase;
    for (int c = 0; c < 8; ++c) {
        int pr = myp[c];
        bool pred = ((pr & 255) == e) || (((pr >> 8) & 255) == e);
        unsigned long long m = __ballot(pred);
        if (lane == 0) wcnt[wave] = (int)__popcll(m);
        __syncthreads();
        int wb = 0;
        for (int w = 0; w < wave; ++w) wb += wcnt[w];
        int ctot = 0;
        for (int w = 0; w < 16; ++w) ctot += wcnt[w];
        if (pred) {
            int wp = (int)__popcll(m & ((1ull << lane) - 1ull));
            frows[base + wb + wp] = c * 1024 + tid;
        }
        base += ctot;
        __syncthreads();
    }
    if (cnt > 0) {
        int first = frows[gbase];
        for (int p = cnt + tid; p < (mytiles << 7); p += 1024) frows[gbase + p] = first;
        if (tid < mytiles) {
            tile_e[tbase + tid] = e;
            int v = cnt - (tid << 7);
            tile_valid[tbase + tid] = v > 128 ? 128 : v;
        }
    }
    if (e == 0 && tid == 0) ntiles[0] = totTiles;
}

// weights f32 -> bf16 (grid-stride, 8 elems/thread)
__global__ void wcvt_kernel(const float* __restrict__ src, unsigned short* __restrict__ dst, int n8) {
    int stride = gridDim.x * blockDim.x;
    for (int i = blockIdx.x * blockDim.x + threadIdx.x; i < n8; i += stride) {
        const float4* p = (const float4*)src + (size_t)i * 2;
        float4 a = p[0], b = p[1];
        uint4 o;
        o.x = (unsigned)f2bf(a.x) | ((unsigned)f2bf(a.y) << 16);
        o.y = (unsigned)f2bf(a.z) | ((unsigned)f2bf(a.w) << 16);
        o.z = (unsigned)f2bf(b.x) | ((unsigned)f2bf(b.y) << 16);
        o.w = (unsigned)f2bf(b.z) | ((unsigned)f2bf(b.w) << 16);
        *(uint4*)(dst + (size_t)i * 8) = o;
    }
}

// GEMM1 (flat over all experts): h = silu(Xg*W1e^T) * (Xg*W3e^T)
// T2 swizzle via rule 21: linear gload_lds dest + inverse-swizzled global SOURCE
// (sslot = (lane&7)^(lane>>3)) + XOR-swizzled ds_read addresses.
// launch_bounds (256,2): 2 waves/SIMD -> 256 unified VGPR+AGPR per lane; this kernel
// needs ~84 VGPR + 128 AGPR. (256,3) caps at ~170 and SPILLS (R5: WRITE_SIZE 118->693MB).
__global__ __launch_bounds__(256, 2)
void gemm1_kernel(const unsigned short* __restrict__ xb,
                  const unsigned short* __restrict__ w1b, const unsigned short* __restrict__ w3b,
                  unsigned short* __restrict__ h_bf,
                  const int* __restrict__ frows, const int* __restrict__ tile_e,
                  const int* __restrict__ ntiles) {
    const int bt = blockIdx.y;
    if (bt >= ntiles[0]) return;
    __shared__ unsigned short aT[128 * 64];
    __shared__ unsigned short b1T[128 * 64];
    __shared__ unsigned short b3T[128 * 64];
    const int e = tile_e[bt];
    const int n0 = blockIdx.x * 128;
    const int tid = threadIdx.x, wave = tid >> 6, lane = tid & 63;
    const int wm = wave >> 1, wn = wave & 1;

    // source swizzle: lane l stages global slot ((l&7)^(l>>3)) into linear LDS pos (l&7)
    const int sslot = (lane & 7) ^ (lane >> 3);
    const unsigned short *aS[4], *b1S[4], *b3S[4];
    unsigned short *aD[4], *b1D[4], *b3D[4];
#pragma unroll
    for (int i = 0; i < 4; ++i) {
        int rowl = wave * 32 + i * 8 + (lane >> 3);
        int tok = frows[bt * 128 + rowl];
        int c8 = sslot * 8;
        aS[i]  = xb  + (size_t)tok * H_DIM + c8;
        b1S[i] = w1b + ((size_t)e * I_DIM + n0 + rowl) * H_DIM + c8;
        b3S[i] = w3b + ((size_t)e * I_DIM + n0 + rowl) * H_DIM + c8;
        int r0l = wave * 32 + i * 8;
        aD[i] = &aT[r0l * 64]; b1D[i] = &b1T[r0l * 64]; b3D[i] = &b3T[r0l * 64];
    }
    f32x4 acc1[4][4] = {};
    f32x4 acc3[4][4] = {};

    for (int kt = 0; kt < H_DIM / 64; ++kt) {
#pragma unroll
        for (int i = 0; i < 4; ++i) {
            gload16(aS[i], aD[i]);
            gload16(b1S[i], b1D[i]);
            gload16(b3S[i], b3D[i]);
            aS[i] += 64; b1S[i] += 64; b3S[i] += 64;
        }
        __syncthreads();
#pragma unroll
        for (int ks = 0; ks < 2; ++ks) {
            const int slot = ks * 4 + (lane >> 4);
            bf16x8 af[4], b1f[4], b3f[4];
#pragma unroll
            for (int m = 0; m < 4; ++m) {
                int row = wm * 64 + m * 16 + (lane & 15);
                af[m] = *(const bf16x8*)&aT[row * 64 + ((slot ^ (row & 7)) << 3)];
            }
#pragma unroll
            for (int n = 0; n < 4; ++n) {
                int row = wn * 64 + n * 16 + (lane & 15);
                int offr = row * 64 + ((slot ^ (row & 7)) << 3);
                b1f[n] = *(const bf16x8*)&b1T[offr];
                b3f[n] = *(const bf16x8*)&b3T[offr];
            }
#pragma unroll
            for (int m = 0; m < 4; ++m)
#pragma unroll
                for (int n = 0; n < 4; ++n) {
                    acc1[m][n] = __builtin_amdgcn_mfma_f32_16x16x32_bf16(af[m], b1f[n], acc1[m][n], 0, 0, 0);
                    acc3[m][n] = __builtin_amdgcn_mfma_f32_16x16x32_bf16(af[m], b3f[n], acc3[m][n], 0, 0, 0);
                }
        }
        __syncthreads();
    }
#pragma unroll
    for (int m = 0; m < 4; ++m)
#pragma unroll
        for (int r = 0; r < 4; ++r) {
            int rowl = wm * 64 + m * 16 + (lane >> 4) * 4 + r;
            size_t hoff = (size_t)(bt * 128 + rowl) * I_DIM;
#pragma unroll
            for (int n = 0; n < 4; ++n) {
                int col = n0 + wn * 64 + n * 16 + (lane & 15);
                float v1 = acc1[m][n][r], v3 = acc3[m][n][r];
                float hv = (v1 / (1.f + expf(-v1))) * v3;
                h_bf[hoff + col] = f2bf(hv);
            }
        }
}

// GEMM2 (flat): out[t,:] += combine[t,e] * (Hg * W2e^T); same swizzle scheme.
// atomicAdd writeback: exactly 2 contributions per element onto zeroed out;
// f32 add commutes => deterministic.
__global__ __launch_bounds__(256, 2)
void gemm2_kernel(const unsigned short* __restrict__ h_bf, const unsigned short* __restrict__ w2b,
                  const float* __restrict__ combine, float* __restrict__ out,
                  const int* __restrict__ frows, const int* __restrict__ tile_e,
                  const int* __restrict__ tile_valid, const int* __restrict__ ntiles) {
    const int bt = blockIdx.y;
    if (bt >= ntiles[0]) return;
    __shared__ unsigned short aT[128 * 64];
    __shared__ unsigned short bT[128 * 64];
    const int e = tile_e[bt];
    const int valid = tile_valid[bt];
    const int n0 = blockIdx.x * 128;
    const int tid = threadIdx.x, wave = tid >> 6, lane = tid & 63;
    const int wm = wave >> 1, wn = wave & 1;

    const int sslot = (lane & 7) ^ (lane >> 3);
    const unsigned short *aS[4], *bS[4];
    unsigned short *aD[4], *bD[4];
#pragma unroll
    for (int i = 0; i < 4; ++i) {
        int rowl = wave * 32 + i * 8 + (lane >> 3);
        int c8 = sslot * 8;
        aS[i] = h_bf + (size_t)(bt * 128 + rowl) * I_DIM + c8;
        bS[i] = w2b + ((size_t)e * H_DIM + n0 + rowl) * I_DIM + c8;
        int r0l = wave * 32 + i * 8;
        aD[i] = &aT[r0l * 64]; bD[i] = &bT[r0l * 64];
    }
    f32x4 acc[4][4] = {};

    for (int kt = 0; kt < I_DIM / 64; ++kt) {
#pragma unroll
        for (int i = 0; i < 4; ++i) {
            gload16(aS[i], aD[i]);
            gload16(bS[i], bD[i]);
            aS[i] += 64; bS[i] += 64;
        }
        __syncthreads();
#pragma unroll
        for (int ks = 0; ks < 2; ++ks) {
            const int slot = ks * 4 + (lane >> 4);
            bf16x8 af[4], bfr[4];
#pragma unroll
            for (int m = 0; m < 4; ++m) {
                int row = wm * 64 + m * 16 + (lane & 15);
                af[m] = *(const bf16x8*)&aT[row * 64 + ((slot ^ (row & 7)) << 3)];
            }
#pragma unroll
            for (int n = 0; n < 4; ++n) {
                int row = wn * 64 + n * 16 + (lane & 15);
                bfr[n] = *(const bf16x8*)&bT[row * 64 + ((slot ^ (row & 7)) << 3)];
            }
#pragma unroll
            for (int m = 0; m < 4; ++m)
#pragma unroll
                for (int n = 0; n < 4; ++n)
                    acc[m][n] = __builtin_amdgcn_mfma_f32_16x16x32_bf16(af[m], bfr[n], acc[m][n], 0, 0, 0);
        }
        __syncthreads();
    }
#pragma unroll
    for (int m = 0; m < 4; ++m)
#pragma unroll
        for (int r = 0; r < 4; ++r) {
            int rowl = wm * 64 + m * 16 + (lane >> 4) * 4 + r;
            if (rowl < valid) {
                int t = frows[bt * 128 + rowl];
                float cmb = combine[(size_t)t * NEXP + e];
#pragma unroll
                for (int n = 0; n < 4; ++n) {
                    int col = n0 + wn * 64 + n * 16 + (lane & 15);
                    atomicAdd(&out[(size_t)t * H_DIM + col], cmb * acc[m][n][r]);
                }
            }
        }
}

// ================= fallback path (R1, verified) =================

__global__ void cvt_x_fb(const float* __restrict__ x, unsigned short* __restrict__ xb) {
    size_t i = (size_t)blockIdx.x * blockDim.x + threadIdx.x;
    const float4* p = (const float4*)x + i * 2;
    float4 a = p[0], b = p[1];
    uint4 o;
    o.x = (unsigned)f2bf(a.x) | ((unsigned)f2bf(a.y) << 16);
    o.y = (unsigned)f2bf(a.z) | ((unsigned)f2bf(a.w) << 16);
    o.z = (unsigned)f2bf(b.x) | ((unsigned)f2bf(b.y) << 16);
    o.w = (unsigned)f2bf(b.z) | ((unsigned)f2bf(b.w) << 16);
    *(uint4*)(xb + i * 8) = o;
}

__global__ void router_fb(const float* __restrict__ x, const float* __restrict__ gw,
                          const float* __restrict__ gb, float* __restrict__ combine,
                          int* __restrict__ rowlist, int* __restrict__ count) {
    int wave = threadIdx.x >> 6, lane = threadIdx.x & 63;
    int t = blockIdx.x * 4 + wave;
    float acc[NEXP];
#pragma unroll
    for (int e = 0; e < NEXP; ++e) acc[e] = 0.f;
    const float4* xr = (const float4*)(x + (size_t)t * H_DIM);
#pragma unroll
    for (int j = 0; j < 4; ++j) {
        int c = j * 64 + lane;
        float4 xv = xr[c];
#pragma unroll
        for (int e = 0; e < NEXP; ++e) {
            float4 gv = ((const float4*)(gw + (size_t)e * H_DIM))[c];
            acc[e] += xv.x * gv.x + xv.y * gv.y + xv.z * gv.z + xv.w * gv.w;
        }
    }
#pragma unroll
    for (int off = 32; off; off >>= 1)
#pragma unroll
        for (int e = 0; e < NEXP; ++e) acc[e] += __shfl_xor(acc[e], off, 64);
    if (lane == 0) {
        float logit[NEXP], mx = -1e30f;
#pragma unroll
        for (int e = 0; e < NEXP; ++e) { logit[e] = acc[e] + gb[e]; mx = fmaxf(mx, logit[e]); }
        float p[NEXP], s = 0.f;
#pragma unroll
        for (int e = 0; e < NEXP; ++e) { p[e] = expf(logit[e] - mx); s += p[e]; }
        float inv = 1.f / s;
#pragma unroll
        for (int e = 0; e < NEXP; ++e) p[e] *= inv;
        int i1 = 0;
#pragma unroll
        for (int e = 1; e < NEXP; ++e) if (p[e] > p[i1]) i1 = e;
        int i2 = -1;
#pragma unroll
        for (int e = 0; e < NEXP; ++e) if (e != i1 && (i2 < 0 || p[e] > p[i2])) i2 = e;
#pragma unroll
        for (int e = 0; e < NEXP; ++e)
            combine[(size_t)t * NEXP + e] = (e == i1 || e == i2) ? p[e] : 0.f;
        int pos1 = atomicAdd(&count[i1], 1); rowlist[i1 * T_TOK + pos1] = t;
        int pos2 = atomicAdd(&count[i2], 1); rowlist[i2 * T_TOK + pos2] = t;
    }
}

__global__ __launch_bounds__(256, 2)
void gemm1_fb(const unsigned short* __restrict__ x_bf,
              const float* __restrict__ w1, const float* __restrict__ w3,
              unsigned short* __restrict__ h_bf,
              const int* __restrict__ rowlist, const int* __restrict__ count, int e) {
    __shared__ unsigned short aT[128 * 64];
    __shared__ unsigned short b1T[128 * 64];
    __shared__ unsigned short b3T[128 * 64];
    __shared__ int rl[128];
    const int cnt = count[e];
    const int r0 = blockIdx.y * 128;
    if (r0 >= cnt) return;
    const int n0 = blockIdx.x * 128;
    const float* __restrict__ w1e = w1 + (size_t)e * I_DIM * H_DIM;
    const float* __restrict__ w3e = w3 + (size_t)e * I_DIM * H_DIM;
    const int tid = threadIdx.x;
    if (tid < 128) {
        int r = r0 + tid;
        rl[tid] = rowlist[e * T_TOK + (r < cnt ? r : 0)];
    }
    __syncthreads();
    const int wave = tid >> 6, lane = tid & 63;
    const int wm = wave >> 1, wn = wave & 1;
    f32x4 acc1[4][4] = {};
    f32x4 acc3[4][4] = {};

    for (int kt = 0; kt < H_DIM / 64; ++kt) {
        const int k0 = kt * 64;
#pragma unroll
        for (int it = 0; it < 4; ++it) {
            int c = it * 256 + tid, row = c >> 3, slot = c & 7;
            uint4 v = *(const uint4*)(x_bf + (size_t)rl[row] * H_DIM + k0 + slot * 8);
            *(uint4*)&aT[row * 64 + ((slot ^ (row & 7)) << 3)] = v;
        }
#pragma unroll
        for (int it = 0; it < 8; ++it) {
            int c = it * 256 + tid, row = c >> 4, cw = c & 15;
            size_t goff = (size_t)(n0 + row) * H_DIM + k0 + cw * 4;
            float4 v1 = *(const float4*)(w1e + goff);
            float4 v3 = *(const float4*)(w3e + goff);
            int offr = row * 64 + (((cw >> 1) ^ (row & 7)) << 3) + (cw & 1) * 4;
            ushort4 p1 = { f2bf(v1.x), f2bf(v1.y), f2bf(v1.z), f2bf(v1.w) };
            ushort4 p3 = { f2bf(v3.x), f2bf(v3.y), f2bf(v3.z), f2bf(v3.w) };
            *(ushort4*)&b1T[offr] = p1;
            *(ushort4*)&b3T[offr] = p3;
        }
        __syncthreads();
#pragma unroll
        for (int ks = 0; ks < 2; ++ks) {
            const int slot = ks * 4 + (lane >> 4);
            bf16x8 af[4], b1f[4], b3f[4];
#pragma unroll
            for (int m = 0; m < 4; ++m) {
                int row = wm * 64 + m * 16 + (lane & 15);
                af[m] = *(const bf16x8*)&aT[row * 64 + ((slot ^ (row & 7)) << 3)];
            }
#pragma unroll
            for (int n = 0; n < 4; ++n) {
                int row = wn * 64 + n * 16 + (lane & 15);
                int offr = row * 64 + ((slot ^ (row & 7)) << 3);
                b1f[n] = *(const bf16x8*)&b1T[offr];
                b3f[n] = *(const bf16x8*)&b3T[offr];
            }
#pragma unroll
            for (int m = 0; m < 4; ++m)
#pragma unroll
                for (int n = 0; n < 4; ++n) {
                    acc1[m][n] = __builtin_amdgcn_mfma_f32_16x16x32_bf16(af[m], b1f[n], acc1[m][n], 0, 0, 0);
                    acc3[m][n] = __builtin_amdgcn_mfma_f32_16x16x32_bf16(af[m], b3f[n], acc3[m][n], 0, 0, 0);
                }
        }
        __syncthreads();
    }
#pragma unroll
    for (int m = 0; m < 4; ++m)
#pragma unroll
        for (int r = 0; r < 4; ++r) {
            int rowl = wm * 64 + m * 16 + (lane >> 4) * 4 + r;
            int ridx = r0 + rowl;
            if (ridx < cnt) {
#pragma unroll
                for (int n = 0; n < 4; ++n) {
                    int col = n0 + wn * 64 + n * 16 + (lane & 15);
                    float v1 = acc1[m][n][r], v3 = acc3[m][n][r];
                    float hv = (v1 / (1.f + expf(-v1))) * v3;
                    h_bf[(size_t)ridx * I_DIM + col] = f2bf(hv);
                }
            }
        }
}

__global__ __launch_bounds__(256, 2)
void gemm2_fb(const unsigned short* __restrict__ h_bf, const float* __restrict__ w2,
              const float* __restrict__ combine, float* __restrict__ out,
              const int* __restrict__ rowlist, const int* __restrict__ count, int e) {
    __shared__ unsigned short aT[128 * 64];
    __shared__ unsigned short bT[128 * 64];
    __shared__ int rl[128];
    const int cnt = count[e];
    const int r0 = blockIdx.y * 128;
    if (r0 >= cnt) return;
    const int n0 = blockIdx.x * 128;
    const float* __restrict__ w2e = w2 + (size_t)e * H_DIM * I_DIM;
    const int tid = threadIdx.x;
    if (tid < 128) {
        int r = r0 + tid;
        rl[tid] = rowlist[e * T_TOK + (r < cnt ? r : 0)];
    }
    __syncthreads();
    const int wave = tid >> 6, lane = tid & 63;
    const int wm = wave >> 1, wn = wave & 1;
    f32x4 acc[4][4] = {};

    for (int kt = 0; kt < I_DIM / 64; ++kt) {
        const int k0 = kt * 64;
#pragma unroll
        for (int it = 0; it < 4; ++it) {
            int c = it * 256 + tid, row = c >> 3, slot = c & 7;
            uint4 v = *(const uint4*)(h_bf + (size_t)(r0 + row) * I_DIM + k0 + slot * 8);
            *(uint4*)&aT[row * 64 + ((slot ^ (row & 7)) << 3)] = v;
        }
#pragma unroll
        for (int it = 0; it < 8; ++it) {
            int c = it * 256 + tid, row = c >> 4, cw = c & 15;
            float4 v = *(const float4*)(w2e + (size_t)(n0 + row) * I_DIM + k0 + cw * 4);
            int offr = row * 64 + (((cw >> 1) ^ (row & 7)) << 3) + (cw & 1) * 4;
            ushort4 p = { f2bf(v.x), f2bf(v.y), f2bf(v.z), f2bf(v.w) };
            *(ushort4*)&bT[offr] = p;
        }
        __syncthreads();
#pragma unroll
        for (int ks = 0; ks < 2; ++ks) {
            const int slot = ks * 4 + (lane >> 4);
            bf16x8 af[4], bfr[4];
#pragma unroll
            for (int m = 0; m < 4; ++m) {
                int row = wm * 64 + m * 16 + (lane & 15);
                af[m] = *(const bf16x8*)&aT[row * 64 + ((slot ^ (row & 7)) << 3)];
            }
#pragma unroll
            for (int n = 0; n < 4; ++n) {
                int row = wn * 64 + n * 16 + (lane & 15);
                bfr[n] = *(const bf16x8*)&bT[row * 64 + ((slot ^ (row & 7)) << 3)];
            }
#pragma unroll
            for (int m = 0; m < 4; ++m)
#pragma unroll
                for (int n = 0; n < 4; ++n)
                    acc[m][n] = __builtin_amdgcn_mfma_f32_16x16x32_bf16(af[m], bfr[n], acc[m][n], 0, 0, 0);
        }
        __syncthreads();
    }
#pragma unroll
    for (int m = 0; m < 4; ++m)
#pragma unroll
        for (int r = 0; r < 4; ++r) {
            int rowl = wm * 64 + m * 16 + (lane >> 4) * 4 + r;
            int ridx = r0 + rowl;
            if (ridx < cnt) {
                int t = rl[rowl];
                float cmb = combine[(size_t)t * NEXP + e];
#pragma unroll
                for (int n = 0; n < 4; ++n) {
                    int col = n0 + wn * 64 + n * 16 + (lane & 15);
                    out[(size_t)t * H_DIM + col] += cmb * acc[m][n][r];
                }
            }
        }
}

// ================= launch =================

extern "C" void kernel_launch(void* const* d_in, const int* in_sizes, int n_in,
                              void* d_out, int out_size, void* d_ws, size_t ws_size,
                              hipStream_t stream) {
    const float* x  = (const float*)d_in[0];
    const float* gw = (const float*)d_in[1];
    const float* gb = (const float*)d_in[2];
    const float* w1 = (const float*)d_in[3];
    const float* w2 = (const float*)d_in[4];
    const float* w3 = (const float*)d_in[5];
    float* out = (float*)d_out;
    char* ws = (char*)d_ws;

    const size_t WELEMS = (size_t)NEXP * I_DIM * H_DIM;      // 29,360,128
    // fast-path layout
    size_t off = 0;
    unsigned short* xb  = (unsigned short*)(ws + off); off += (size_t)T_TOK * H_DIM * 2;       // 16 MB
    unsigned short* w1b = (unsigned short*)(ws + off); off += WELEMS * 2;                      // 56 MB
    unsigned short* w3b = (unsigned short*)(ws + off); off += WELEMS * 2;
    unsigned short* w2b = (unsigned short*)(ws + off); off += WELEMS * 2;
    unsigned short* hb  = (unsigned short*)(ws + off); off += (size_t)MAX_TILES * 128 * I_DIM * 2; // 119 MB
    float* combine      = (float*)(ws + off);          off += (size_t)T_TOK * NEXP * 4;
    int* pair           = (int*)(ws + off);            off += (size_t)T_TOK * 4;
    int* frows          = (int*)(ws + off);            off += (size_t)MAX_TILES * 128 * 4;
    int* tile_e         = (int*)(ws + off);            off += 1024;
    int* tile_valid     = (int*)(ws + off);            off += 1024;
    int* ntiles         = (int*)(ws + off);            off += 1024;
    const size_t WS_NEEDED = off;

    (void)hipMemsetAsync(out, 0, (size_t)T_TOK * H_DIM * sizeof(float), stream);

    if (ws_size >= WS_NEEDED) {
        const int n8 = (int)(WELEMS / 8);
        wcvt_kernel<<<dim3(2048), dim3(256), 0, stream>>>(w1, w1b, n8);
        wcvt_kernel<<<dim3(2048), dim3(256), 0, stream>>>(w3, w3b, n8);
        wcvt_kernel<<<dim3(2048), dim3(256), 0, stream>>>(w2, w2b, n8);
        router_kernel<<<dim3(T_TOK / 4), dim3(256), 0, stream>>>(x, gw, gb, xb, combine, pair);
        build_lists_kernel<<<dim3(NEXP), dim3(1024), 0, stream>>>(pair, frows, tile_e, tile_valid, ntiles);
        gemm1_kernel<<<dim3(I_DIM / 128, MAX_TILES), dim3(256), 0, stream>>>(
            xb, w1b, w3b, hb, frows, tile_e, ntiles);
        gemm2_kernel<<<dim3(H_DIM / 128, MAX_TILES), dim3(256), 0, stream>>>(
            hb, w2b, combine, out, frows, tile_e, tile_valid, ntiles);
    } else {
        // fallback: R1 layout (76 MB)
        unsigned short* x_bf    = (unsigned short*)ws;
        unsigned short* h_bf    = (unsigned short*)(ws + 16777216);
        float*          fcomb   = (float*)(ws + 16777216 + 58720256);
        int*            rowlist = (int*)(ws + 16777216 + 58720256 + 262144);
        int*            count   = (int*)(ws + 16777216 + 58720256 + 262144 + 262144);

        (void)hipMemsetAsync(count, 0, NEXP * sizeof(int), stream);
        cvt_x_fb<<<dim3(T_TOK * H_DIM / (256 * 8)), dim3(256), 0, stream>>>(x, x_bf);
        router_fb<<<dim3(T_TOK / 4), dim3(256), 0, stream>>>(x, gw, gb, fcomb, rowlist, count);
        for (int e = 0; e < NEXP; ++e) {
            gemm1_fb<<<dim3(I_DIM / 128, T_TOK / 128), dim3(256), 0, stream>>>(
                x_bf, w1, w3, h_bf, rowlist, count, e);
            gemm2_fb<<<dim3(H_DIM / 128, T_TOK / 128), dim3(256), 0, stream>>>(
                h_bf, w2, fcomb, out, rowlist, count, e);
        }
    }
}